// Round 13
// baseline (216.289 us; speedup 1.0000x reference)
//
#include <hip/hip_runtime.h>
#include <hip/hip_bf16.h>

typedef __hip_bfloat16 bf16;
typedef __attribute__((ext_vector_type(8))) short short8v;          // 8 bf16 (4 VGPRs)
typedef __attribute__((ext_vector_type(8))) unsigned short ushort8v;
typedef __attribute__((ext_vector_type(4))) unsigned short ushort4v;
typedef __attribute__((ext_vector_type(4))) float float4v;

__device__ __forceinline__ float bfu2f(unsigned short u) {
    union { unsigned int i; float f; } v; v.i = ((unsigned int)u) << 16; return v.f;
}
__device__ __forceinline__ unsigned short f2bfu_rn(float x) {
    union { float f; unsigned int i; } u; u.f = x;
    unsigned int r = (u.i + 0x7FFFu + ((u.i >> 16) & 1u)) >> 16;
    return (unsigned short)r;
}

// ---------- cast+transpose weights: W[k][n] fp32 -> Wt[n][k] bf16. grid (4,4,4) ----------
__global__ __launch_bounds__(256) void cast_wt(
    const float* __restrict__ Wq, const float* __restrict__ Wk,
    const float* __restrict__ Wv, const float* __restrict__ Wp,
    unsigned short* __restrict__ wt)
{
    __shared__ unsigned short tile[64][72];
    const float* W = (blockIdx.z == 0) ? Wq : (blockIdx.z == 1) ? Wk
                   : (blockIdx.z == 2) ? Wv : Wp;
    unsigned short* WT = wt + (size_t)blockIdx.z * 65536;
    const int t = threadIdx.x;
    const int k0 = blockIdx.x * 64, n0 = blockIdx.y * 64;
    {
        const int r = t >> 2, cseg = (t & 3) * 16;
        const float* src = W + (size_t)(k0 + r) * 256 + n0 + cseg;
        #pragma unroll
        for (int j = 0; j < 16; ++j) tile[r][cseg + j] = f2bfu_rn(src[j]);
    }
    __syncthreads();
    {
        const int ch = t & 63, lq = t >> 6;
        ushort8v o0, o1;
        #pragma unroll
        for (int i = 0; i < 8; ++i) o0[i] = tile[lq * 16 + i][ch];
        #pragma unroll
        for (int i = 0; i < 8; ++i) o1[i] = tile[lq * 16 + 8 + i][ch];
        unsigned short* dst = WT + (size_t)(n0 + ch) * 256 + k0 + lq * 16;
        *(ushort8v*)(dst)     = o0;
        *(ushort8v*)(dst + 8) = o1;
    }
}

// ---------- MFMA projection core: 16 m-rows x 128 n-cols per wave ----------
__device__ __forceinline__ void proj_core(
    const float* __restrict__ aptr, const unsigned short* __restrict__ Wt,
    int nc0, int m16, int quad, float4v acc[8])
{
    #pragma unroll
    for (int i = 0; i < 8; ++i) acc[i] = (float4v){0.f, 0.f, 0.f, 0.f};
    #pragma unroll
    for (int ks = 0; ks < 8; ++ks) {
        float4 a0 = *(const float4*)(aptr + ks * 32);
        float4 a1 = *(const float4*)(aptr + ks * 32 + 4);
        short8v af;
        af[0] = (short)f2bfu_rn(a0.x); af[1] = (short)f2bfu_rn(a0.y);
        af[2] = (short)f2bfu_rn(a0.z); af[3] = (short)f2bfu_rn(a0.w);
        af[4] = (short)f2bfu_rn(a1.x); af[5] = (short)f2bfu_rn(a1.y);
        af[6] = (short)f2bfu_rn(a1.z); af[7] = (short)f2bfu_rn(a1.w);
        #pragma unroll
        for (int i = 0; i < 8; ++i) {
            short8v bfr = *(const short8v*)(Wt + (size_t)(nc0 + i * 16 + m16) * 256 + ks * 32 + quad * 8);
            acc[i] = __builtin_amdgcn_mfma_f32_16x16x32_bf16(af, bfr, acc[i], 0, 0, 0);
        }
    }
}

// ---------- fused q/k/v projections. grid 691: [0,19) q, [19,355) k, [355,691) v ----------
__global__ __launch_bounds__(256) void proj_all(
    const float* __restrict__ q, const float* __restrict__ k, const float* __restrict__ v,
    const unsigned short* __restrict__ wt,
    unsigned short* __restrict__ qb, unsigned short* __restrict__ kb,
    unsigned short* __restrict__ vt)
{
    const int t = threadIdx.x;
    const int wave = t >> 6, lane = t & 63;
    const int m16 = lane & 15, quad = lane >> 4;
    const int msub = (wave & 1) * 16;
    const int nc0 = (wave >> 1) * 128;
    const int bx = blockIdx.x;

    float4v acc[8];
    if (bx < 19) {                       // ---- query -> qb (row-major), M=600
        const int m0 = bx * 32;
        const int arow = min(m0 + msub + m16, 599);
        proj_core(q + (size_t)arow * 256 + quad * 8, wt, nc0, m16, quad, acc);
        #pragma unroll
        for (int i = 0; i < 8; ++i)
            #pragma unroll
            for (int r = 0; r < 4; ++r) {
                int m = m0 + msub + quad * 4 + r;
                if (m < 600)
                    qb[(size_t)m * 256 + nc0 + i * 16 + m16] = f2bfu_rn(acc[i][r]);
            }
    } else if (bx < 355) {               // ---- key -> kb (row-major), M=10752
        const int m0 = (bx - 19) * 32;
        proj_core(k + (size_t)(m0 + msub + m16) * 256 + quad * 8, wt + 65536, nc0, m16, quad, acc);
        #pragma unroll
        for (int i = 0; i < 8; ++i)
            #pragma unroll
            for (int r = 0; r < 4; ++r) {
                int m = m0 + msub + quad * 4 + r;
                kb[(size_t)m * 256 + nc0 + i * 16 + m16] = f2bfu_rn(acc[i][r]);
            }
    } else {                             // ---- value -> vt (transposed), M=10752
        const int m0 = (bx - 355) * 32;
        proj_core(v + (size_t)(m0 + msub + m16) * 256 + quad * 8, wt + 131072, nc0, m16, quad, acc);
        const int bb = (m0 >= 5376) ? 1 : 0;
        const int lcol = m0 - bb * 5376 + msub + quad * 4;
        #pragma unroll
        for (int i = 0; i < 8; ++i) {
            const int ch = nc0 + i * 16 + m16;
            ushort4v p;
            #pragma unroll
            for (int r = 0; r < 4; ++r) p[r] = f2bfu_rn(acc[i][r]);
            *(ushort4v*)(vt + (size_t)(bb * 256 + ch) * 5376 + lcol) = p;
        }
    }
}

// ---------- fused QK + softmax + PV, l-split x7, XCD-swizzled. grid 2128, 512 thr ----------
// Block i -> XCD i&7 (heuristic): each XCD owns 2 (b,h) groups so k/vt slices stay
// in its L2. Wave w of z-chunk zz owns l in [zz*768 + w*96, +96).
__global__ __launch_bounds__(512) void attn_fused(
    const unsigned short* __restrict__ qb, const unsigned short* __restrict__ kb,
    const unsigned short* __restrict__ vt,
    unsigned short* __restrict__ attn, float* __restrict__ xbp, float* __restrict__ Sp)
{
    __shared__ unsigned short probs[8][16 * 104];   // 26,624 B (stride 104: aligned, low-conflict)
    __shared__ float partial[8][64][9];             // 18,432 B
    __shared__ float SrowP[8][16];

    const int t = threadIdx.x;
    const int wave = t >> 6, lane = t & 63;

    // XCD-aware decode: i&7 = XCD, each XCD gets bh = 2c, 2c+1 (133 blocks each)
    const int i0 = blockIdx.x;
    const int c = i0 & 7;
    int m = i0 >> 3;                    // 0..265
    const int half = (m >= 133) ? 1 : 0;
    const int bh = c * 2 + half;
    m -= half * 133;
    const int n0 = (m % 19) * 16;
    const int zz = m / 19;              // 0..6

    const int b = bh >> 3, h = bh & 7;
    const int m16 = lane & 15, quad = lane >> 4;
    const float scale = 0.17677669529663687f;   // 1/sqrt(32)

    const unsigned short* qp = qb + (size_t)(b * 300 + min(n0 + m16, 299)) * 256 + h * 32 + quad * 8;
    const short8v qfrag = *(const short8v*)qp;

    const unsigned short* kbase = kb + (size_t)(b * 5376) * 256 + h * 32 + quad * 8;
    const unsigned short* vt0 = vt + (size_t)(b * 256 + h * 32 + m16) * 5376;
    const unsigned short* vt1 = vt0 + (size_t)16 * 5376;

    unsigned short* pw = &probs[wave][0];
    const int lc = zz * 768 + wave * 96;

    float4v c0 = {0.f, 0.f, 0.f, 0.f};
    float4v c1 = {0.f, 0.f, 0.f, 0.f};
    float sm = 0.f;

    // ---- QK: 6 tiles of 16 l. A = k (m=l), B = q (n=n). C: row=l, col=n.
    #pragma unroll
    for (int i = 0; i < 6; ++i) {
        const int lcol = lc + i * 16 + m16;
        short8v kf = *(const short8v*)(kbase + (size_t)lcol * 256);
        float4v c = {0.f, 0.f, 0.f, 0.f};
        c = __builtin_amdgcn_mfma_f32_16x16x32_bf16(kf, qfrag, c, 0, 0, 0);
        ushort4v pk;
        #pragma unroll
        for (int r = 0; r < 4; ++r) pk[r] = f2bfu_rn(c[r] * scale);
        *(ushort4v*)(pw + m16 * 104 + i * 16 + quad * 4) = pk;
    }

    // ---- flush logits to global attn (for the mask kernel)
    {
        const int row = lane >> 2;
        const int n = n0 + row;
        if (n < 300) {
            unsigned short* gdst = attn + ((size_t)(b * 300 + n) * 8 + h) * 5376 + lc;
            const unsigned short* lsrc = pw + row * 104;
            #pragma unroll
            for (int it = 0; it < 3; ++it) {
                const int colk = (lane & 3) * 8 + it * 32;
                *(ushort8v*)(gdst + colk) = *(const ushort8v*)(lsrc + colk);
            }
        }
    }

    // ---- PV: 3 K-steps of 32 l. A[m=n=m16][k=l], exp on read.
    #pragma unroll
    for (int step = 0; step < 3; ++step) {
        const int lloc = step * 32 + quad * 8;
        ushort8v ua = *(const ushort8v*)(pw + m16 * 104 + lloc);
        short8v af;
        #pragma unroll
        for (int j = 0; j < 8; ++j) {
            float e = __expf(bfu2f(ua[j]));
            sm += e;
            af[j] = (short)f2bfu_rn(e);
        }
        const int lg = lc + lloc;
        short8v b0 = *(const short8v*)(vt0 + lg);
        short8v b1 = *(const short8v*)(vt1 + lg);
        c0 = __builtin_amdgcn_mfma_f32_16x16x32_bf16(af, b0, c0, 0, 0, 0);
        c1 = __builtin_amdgcn_mfma_f32_16x16x32_bf16(af, b1, c1, 0, 0, 0);
    }

    sm += __shfl_xor(sm, 16);
    sm += __shfl_xor(sm, 32);
    if (lane < 16) SrowP[wave][lane] = sm;
    #pragma unroll
    for (int j = 0; j < 4; ++j) {
        partial[wave][lane][j]     = c0[j];
        partial[wave][lane][4 + j] = c1[j];
    }
    __syncthreads();

    if (t < 64) {
        float acc[8] = {0.f, 0.f, 0.f, 0.f, 0.f, 0.f, 0.f, 0.f};
        #pragma unroll
        for (int w = 0; w < 8; ++w)
            #pragma unroll
            for (int j = 0; j < 8; ++j) acc[j] += partial[w][t][j];

        const int d = t & 15, q = t >> 4;
        float* xplane = xbp + (size_t)zz * 153600;
        float* splane = Sp + (size_t)zz * 4800;
        #pragma unroll
        for (int r = 0; r < 4; ++r) {
            const int row = q * 4 + r;
            const int nn = n0 + row;
            if (nn < 300) {
                float S = 0.f;
                #pragma unroll
                for (int w = 0; w < 8; ++w) S += SrowP[w][row];
                if (d == 0) splane[(size_t)(b * 300 + nn) * 8 + h] = S;
                float* o = xplane + (size_t)(b * 300 + nn) * 256 + h * 32 + d;
                o[0]  = acc[r];
                o[16] = acc[4 + r];
            }
        }
    }
}

// ---------- output projection with fused cross-z combine + 1/S. grid 19 ----------
__global__ __launch_bounds__(256) void proj_out(
    const float* __restrict__ xbp, const float* __restrict__ Sp,
    const unsigned short* __restrict__ Wtp,
    const float* __restrict__ bp, float* __restrict__ out)
{
    const int t = threadIdx.x;
    const int wave = t >> 6, lane = t & 63;
    const int m16 = lane & 15, quad = lane >> 4;
    const int msub = (wave & 1) * 16;
    const int nc0 = (wave >> 1) * 128;
    const int m0 = blockIdx.x * 32;

    const int arow = min(m0 + msub + m16, 599);
    const float* a0p = xbp + (size_t)arow * 256 + quad * 8;

    float4v acc[8];
    #pragma unroll
    for (int i = 0; i < 8; ++i) acc[i] = (float4v){0.f, 0.f, 0.f, 0.f};

    #pragma unroll
    for (int ks = 0; ks < 8; ++ks) {
        float S = 0.f;
        #pragma unroll
        for (int z = 0; z < 7; ++z) S += Sp[(size_t)z * 4800 + (size_t)arow * 8 + ks];
        const float rS = 1.0f / S;
        float a[8];
        #pragma unroll
        for (int half = 0; half < 2; ++half) {
            const float* p = a0p + ks * 32 + half * 4;
            float sx = 0.f, sy = 0.f, sz = 0.f, sw = 0.f;
            #pragma unroll
            for (int z = 0; z < 7; ++z) {
                float4 x = *(const float4*)(p + (size_t)z * 153600);
                sx += x.x; sy += x.y; sz += x.z; sw += x.w;
            }
            a[half * 4 + 0] = sx * rS;
            a[half * 4 + 1] = sy * rS;
            a[half * 4 + 2] = sz * rS;
            a[half * 4 + 3] = sw * rS;
        }
        short8v af;
        #pragma unroll
        for (int j = 0; j < 8; ++j) af[j] = (short)f2bfu_rn(a[j]);
        #pragma unroll
        for (int i = 0; i < 8; ++i) {
            short8v bfr = *(const short8v*)(Wtp + (size_t)(nc0 + i * 16 + m16) * 256 + ks * 32 + quad * 8);
            acc[i] = __builtin_amdgcn_mfma_f32_16x16x32_bf16(af, bfr, acc[i], 0, 0, 0);
        }
    }

    #pragma unroll
    for (int i = 0; i < 8; ++i) {
        const float bv = bp[nc0 + i * 16 + m16];
        #pragma unroll
        for (int r = 0; r < 4; ++r) {
            int m = m0 + msub + quad * 4 + r;
            if (m < 600)
                out[(size_t)m * 256 + nc0 + i * 16 + m16] = acc[i][r] + bv;
        }
    }
}

// ---------- mask branch: folded scalar fields + 8-pixel vector loads. grid (600,2) ----------
__global__ __launch_bounds__(256) void mask_kernel(
    const bf16* __restrict__ attn,
    const float* __restrict__ W1, const float* __restrict__ b1,
    const float* __restrict__ W2, const float* __restrict__ b2,
    const float* __restrict__ W3, const float* __restrict__ b3,
    const float* __restrict__ Wm, const float* __restrict__ bmp,
    float* __restrict__ out)
{
    __shared__ float g2s[1024];
    __shared__ float g3s[256];
    __shared__ float w1s[64], w2s[64], w3s[64];
    __shared__ float b1s[8], b2s[8], b3s[8];
    __shared__ float wms[24];
    __shared__ float bms;

    const int t  = threadIdx.x;
    const int bn = blockIdx.x;
    const int ph = blockIdx.y;             // pixel half: 0 or 1
    const unsigned short* ap = (const unsigned short*)attn + (size_t)bn * 8 * 5376;

    if (t < 64) { w1s[t] = W1[t]; w2s[t] = W2[t]; w3s[t] = W3[t]; }
    if (t < 8)  { b1s[t] = b1[t]; b2s[t] = b2[t]; b3s[t] = b3[t]; }
    if (t < 24) wms[t] = Wm[t];
    if (t == 0) bms = bmp[0];
    __syncthreads();

    {
        const int l2 = t * 4;
        ushort4v u[8];
        #pragma unroll
        for (int hh = 0; hh < 8; ++hh)
            u[hh] = *(const ushort4v*)(ap + hh * 5376 + 4096 + l2);
        #pragma unroll
        for (int pp = 0; pp < 4; ++pp) {
            float g = 0.f;
            #pragma unroll
            for (int hh = 0; hh < 8; ++hh) {
                float s = b2s[hh];
                #pragma unroll
                for (int hp = 0; hp < 8; ++hp) s += bfu2f(u[hp][pp]) * w2s[hp * 8 + hh];
                g += fmaxf(s, 0.f) * wms[8 + hh];
            }
            g2s[l2 + pp] = g;
        }
    }
    if (t < 64) {
        const int l3 = t * 4;
        ushort4v u[8];
        #pragma unroll
        for (int hh = 0; hh < 8; ++hh)
            u[hh] = *(const ushort4v*)(ap + hh * 5376 + 5120 + l3);
        #pragma unroll
        for (int pp = 0; pp < 4; ++pp) {
            float g = 0.f;
            #pragma unroll
            for (int hh = 0; hh < 8; ++hh) {
                float s = b3s[hh];
                #pragma unroll
                for (int hp = 0; hp < 8; ++hp) s += bfu2f(u[hp][pp]) * w3s[hp * 8 + hh];
                g += fmaxf(s, 0.f) * wms[16 + hh];
            }
            g3s[l3 + pp] = g;
        }
    }
    __syncthreads();

    {
        const int p0 = ph * 2048 + t * 8;
        ushort8v u[8];
        #pragma unroll
        for (int hh = 0; hh < 8; ++hh)
            u[hh] = *(const ushort8v*)(ap + hh * 5376 + p0);

        float res[8];
        #pragma unroll
        for (int pp = 0; pp < 8; ++pp) {
            const int p = p0 + pp;
            const int Y = p >> 6, X = p & 63;

            float acc = bms;
            #pragma unroll
            for (int hh = 0; hh < 8; ++hh) {
                float s = b1s[hh];
                #pragma unroll
                for (int hp = 0; hp < 8; ++hp) s += bfu2f(u[hp][pp]) * w1s[hp * 8 + hh];
                acc += fmaxf(s, 0.f) * wms[hh];
            }
            {
                float ry = fminf(fmaxf(0.5f * Y - 0.25f, 0.f), 31.f);
                float rx = fminf(fmaxf(0.5f * X - 0.25f, 0.f), 31.f);
                int y0 = (int)ry, x0 = (int)rx;
                int y1 = min(y0 + 1, 31), x1 = min(x0 + 1, 31);
                float wy = ry - (float)y0, wx = rx - (float)x0;
                acc += (g2s[y0 * 32 + x0] * (1.f - wx) + g2s[y0 * 32 + x1] * wx) * (1.f - wy)
                     + (g2s[y1 * 32 + x0] * (1.f - wx) + g2s[y1 * 32 + x1] * wx) * wy;
            }
            {
                float ry = fminf(fmaxf(0.25f * Y - 0.375f, 0.f), 15.f);
                float rx = fminf(fmaxf(0.25f * X - 0.375f, 0.f), 15.f);
                int y0 = (int)ry, x0 = (int)rx;
                int y1 = min(y0 + 1, 15), x1 = min(x0 + 1, 15);
                float wy = ry - (float)y0, wx = rx - (float)x0;
                acc += (g3s[y0 * 16 + x0] * (1.f - wx) + g3s[y0 * 16 + x1] * wx) * (1.f - wy)
                     + (g3s[y1 * 16 + x0] * (1.f - wx) + g3s[y1 * 16 + x1] * wx) * wy;
            }
            res[pp] = fmaxf(acc, 0.f);
        }
        float* o = out + 153600 + (size_t)bn * 4096 + p0;
        #pragma unroll
        for (int pp = 0; pp < 8; ++pp) o[pp] = res[pp];
    }
}

// ---------- launch ----------
extern "C" void kernel_launch(void* const* d_in, const int* in_sizes, int n_in,
                              void* d_out, int out_size, void* d_ws, size_t ws_size,
                              hipStream_t stream) {
    const float* query = (const float*)d_in[0];
    const float* key   = (const float*)d_in[1];
    const float* value = (const float*)d_in[2];
    const float* Wq = (const float*)d_in[5];
    const float* Wk = (const float*)d_in[6];
    const float* Wv = (const float*)d_in[7];
    const float* Wp = (const float*)d_in[8];
    const float* bp = (const float*)d_in[9];
    const float* W1 = (const float*)d_in[10];
    const float* b1 = (const float*)d_in[11];
    const float* W2 = (const float*)d_in[12];
    const float* b2 = (const float*)d_in[13];
    const float* W3 = (const float*)d_in[14];
    const float* b3 = (const float*)d_in[15];
    const float* Wm = (const float*)d_in[16];
    const float* bm = (const float*)d_in[17];
    float* out = (float*)d_out;

    char* ws = (char*)d_ws;
    unsigned short* wt = (unsigned short*)(ws);       // 4*65536 bf16 = 524,288 B
    bf16*  qb   = (bf16*) (ws + 524288);              // 600*256 bf16
    bf16*  kb   = (bf16*) (ws + 831488);              // 10752*256 bf16
    bf16*  vt   = (bf16*) (ws + 6336512);             // 512*5376 bf16
    bf16*  attn = (bf16*) (ws + 11841536);            // 600*8*5376 bf16
    float* xbp  = (float*)(ws + 63451136);            // 7*600*256 fp32 = 4,300,800 B
    float* Sp   = (float*)(ws + 67751936);            // 7*4800 fp32    =   134,400 B

    cast_wt<<<dim3(4, 4, 4), 256, 0, stream>>>(Wq, Wk, Wv, Wp, wt);

    proj_all<<<691, 256, 0, stream>>>(query, key, value, wt,
        (unsigned short*)qb, (unsigned short*)kb, (unsigned short*)vt);

    attn_fused<<<2128, 512, 0, stream>>>(
        (const unsigned short*)qb, (const unsigned short*)kb, (const unsigned short*)vt,
        (unsigned short*)attn, xbp, Sp);

    mask_kernel<<<dim3(600, 2), 256, 0, stream>>>(attn, W1, b1, W2, b2, W3, b3, Wm, bm, out);

    proj_out<<<19, 256, 0, stream>>>(xbp, Sp, (const unsigned short*)wt + 196608, bp, out);
}

// Round 14
// 204.060 us; speedup vs baseline: 1.0599x; 1.0599x over previous
//
#include <hip/hip_runtime.h>
#include <hip/hip_bf16.h>

typedef __hip_bfloat16 bf16;
typedef __attribute__((ext_vector_type(8))) short short8v;          // 8 bf16 (4 VGPRs)
typedef __attribute__((ext_vector_type(8))) unsigned short ushort8v;
typedef __attribute__((ext_vector_type(4))) unsigned short ushort4v;
typedef __attribute__((ext_vector_type(4))) float float4v;

__device__ __forceinline__ float bfu2f(unsigned short u) {
    union { unsigned int i; float f; } v; v.i = ((unsigned int)u) << 16; return v.f;
}
__device__ __forceinline__ unsigned short f2bfu_rn(float x) {
    union { float f; unsigned int i; } u; u.f = x;
    unsigned int r = (u.i + 0x7FFFu + ((u.i >> 16) & 1u)) >> 16;
    return (unsigned short)r;
}

// ---------- cast+transpose weights: W[k][n] fp32 -> Wt[n][k] bf16. grid (4,4,4) ----------
__global__ __launch_bounds__(256) void cast_wt(
    const float* __restrict__ Wq, const float* __restrict__ Wk,
    const float* __restrict__ Wv, const float* __restrict__ Wp,
    unsigned short* __restrict__ wt)
{
    __shared__ unsigned short tile[64][72];
    const float* W = (blockIdx.z == 0) ? Wq : (blockIdx.z == 1) ? Wk
                   : (blockIdx.z == 2) ? Wv : Wp;
    unsigned short* WT = wt + (size_t)blockIdx.z * 65536;
    const int t = threadIdx.x;
    const int k0 = blockIdx.x * 64, n0 = blockIdx.y * 64;
    {
        const int r = t >> 2, cseg = (t & 3) * 16;
        const float* src = W + (size_t)(k0 + r) * 256 + n0 + cseg;
        #pragma unroll
        for (int j = 0; j < 16; ++j) tile[r][cseg + j] = f2bfu_rn(src[j]);
    }
    __syncthreads();
    {
        const int ch = t & 63, lq = t >> 6;
        ushort8v o0, o1;
        #pragma unroll
        for (int i = 0; i < 8; ++i) o0[i] = tile[lq * 16 + i][ch];
        #pragma unroll
        for (int i = 0; i < 8; ++i) o1[i] = tile[lq * 16 + 8 + i][ch];
        unsigned short* dst = WT + (size_t)(n0 + ch) * 256 + k0 + lq * 16;
        *(ushort8v*)(dst)     = o0;
        *(ushort8v*)(dst + 8) = o1;
    }
}

// ---------- MFMA projection core: 16 m-rows x 128 n-cols per wave ----------
__device__ __forceinline__ void proj_core(
    const float* __restrict__ aptr, const unsigned short* __restrict__ Wt,
    int nc0, int m16, int quad, float4v acc[8])
{
    #pragma unroll
    for (int i = 0; i < 8; ++i) acc[i] = (float4v){0.f, 0.f, 0.f, 0.f};
    #pragma unroll
    for (int ks = 0; ks < 8; ++ks) {
        float4 a0 = *(const float4*)(aptr + ks * 32);
        float4 a1 = *(const float4*)(aptr + ks * 32 + 4);
        short8v af;
        af[0] = (short)f2bfu_rn(a0.x); af[1] = (short)f2bfu_rn(a0.y);
        af[2] = (short)f2bfu_rn(a0.z); af[3] = (short)f2bfu_rn(a0.w);
        af[4] = (short)f2bfu_rn(a1.x); af[5] = (short)f2bfu_rn(a1.y);
        af[6] = (short)f2bfu_rn(a1.z); af[7] = (short)f2bfu_rn(a1.w);
        #pragma unroll
        for (int i = 0; i < 8; ++i) {
            short8v bfr = *(const short8v*)(Wt + (size_t)(nc0 + i * 16 + m16) * 256 + ks * 32 + quad * 8);
            acc[i] = __builtin_amdgcn_mfma_f32_16x16x32_bf16(af, bfr, acc[i], 0, 0, 0);
        }
    }
}

// ---------- fused q/k/v projections. grid 691: [0,19) q, [19,355) k, [355,691) v ----------
__global__ __launch_bounds__(256) void proj_all(
    const float* __restrict__ q, const float* __restrict__ k, const float* __restrict__ v,
    const unsigned short* __restrict__ wt,
    unsigned short* __restrict__ qb, unsigned short* __restrict__ kb,
    unsigned short* __restrict__ vt)
{
    const int t = threadIdx.x;
    const int wave = t >> 6, lane = t & 63;
    const int m16 = lane & 15, quad = lane >> 4;
    const int msub = (wave & 1) * 16;
    const int nc0 = (wave >> 1) * 128;
    const int bx = blockIdx.x;

    float4v acc[8];
    if (bx < 19) {                       // ---- query -> qb (row-major), M=600
        const int m0 = bx * 32;
        const int arow = min(m0 + msub + m16, 599);
        proj_core(q + (size_t)arow * 256 + quad * 8, wt, nc0, m16, quad, acc);
        #pragma unroll
        for (int i = 0; i < 8; ++i)
            #pragma unroll
            for (int r = 0; r < 4; ++r) {
                int m = m0 + msub + quad * 4 + r;
                if (m < 600)
                    qb[(size_t)m * 256 + nc0 + i * 16 + m16] = f2bfu_rn(acc[i][r]);
            }
    } else if (bx < 355) {               // ---- key -> kb (row-major), M=10752
        const int m0 = (bx - 19) * 32;
        proj_core(k + (size_t)(m0 + msub + m16) * 256 + quad * 8, wt + 65536, nc0, m16, quad, acc);
        #pragma unroll
        for (int i = 0; i < 8; ++i)
            #pragma unroll
            for (int r = 0; r < 4; ++r) {
                int m = m0 + msub + quad * 4 + r;
                kb[(size_t)m * 256 + nc0 + i * 16 + m16] = f2bfu_rn(acc[i][r]);
            }
    } else {                             // ---- value -> vt (transposed), M=10752
        const int m0 = (bx - 355) * 32;
        proj_core(v + (size_t)(m0 + msub + m16) * 256 + quad * 8, wt + 131072, nc0, m16, quad, acc);
        const int bb = (m0 >= 5376) ? 1 : 0;
        const int lcol = m0 - bb * 5376 + msub + quad * 4;
        #pragma unroll
        for (int i = 0; i < 8; ++i) {
            const int ch = nc0 + i * 16 + m16;
            ushort4v p;
            #pragma unroll
            for (int r = 0; r < 4; ++r) p[r] = f2bfu_rn(acc[i][r]);
            *(ushort4v*)(vt + (size_t)(bb * 256 + ch) * 5376 + lcol) = p;
        }
    }
}

// ---------- fused QK + softmax + PV, l-split x3 (round-12 config). grid (19,16,3), 512 thr ----------
__global__ __launch_bounds__(512) void attn_fused(
    const unsigned short* __restrict__ qb, const unsigned short* __restrict__ kb,
    const unsigned short* __restrict__ vt,
    unsigned short* __restrict__ attn, float* __restrict__ xbp, float* __restrict__ Sp)
{
    __shared__ unsigned short probs[8][16 * 236];   // 60,416 B
    __shared__ float partial[8][64][9];             // 18,432 B
    __shared__ float SrowP[8][16];

    const int t = threadIdx.x;
    const int wave = t >> 6, lane = t & 63;
    const int n0 = blockIdx.x * 16;
    const int bh = blockIdx.y;
    const int zz = blockIdx.z;
    const int b = bh >> 3, h = bh & 7;
    const int m16 = lane & 15, quad = lane >> 4;
    const float scale = 0.17677669529663687f;   // 1/sqrt(32)

    const unsigned short* qp = qb + (size_t)(b * 300 + min(n0 + m16, 299)) * 256 + h * 32 + quad * 8;
    const short8v qfrag = *(const short8v*)qp;

    const unsigned short* kbase = kb + (size_t)(b * 5376) * 256 + h * 32 + quad * 8;
    const unsigned short* vt0 = vt + (size_t)(b * 256 + h * 32 + m16) * 5376;
    const unsigned short* vt1 = vt0 + (size_t)16 * 5376;

    unsigned short* pw = &probs[wave][0];
    const int lc = zz * 1792 + wave * 224;

    float4v c0 = {0.f, 0.f, 0.f, 0.f};
    float4v c1 = {0.f, 0.f, 0.f, 0.f};
    float sm = 0.f;

    // ---- QK: 14 tiles of 16 l. A = k (m=l), B = q (n=n). C: row=l, col=n.
    #pragma unroll
    for (int i = 0; i < 14; ++i) {
        const int lcol = lc + i * 16 + m16;
        short8v kf = *(const short8v*)(kbase + (size_t)lcol * 256);
        float4v c = {0.f, 0.f, 0.f, 0.f};
        c = __builtin_amdgcn_mfma_f32_16x16x32_bf16(kf, qfrag, c, 0, 0, 0);
        ushort4v pk;
        #pragma unroll
        for (int r = 0; r < 4; ++r) pk[r] = f2bfu_rn(c[r] * scale);
        *(ushort4v*)(pw + m16 * 236 + i * 16 + quad * 4) = pk;
    }

    // ---- flush logits to global attn (for the mask kernels)
    {
        const int row = lane >> 2;
        const int n = n0 + row;
        if (n < 300) {
            unsigned short* gdst = attn + ((size_t)(b * 300 + n) * 8 + h) * 5376 + lc;
            const unsigned short* lsrc = pw + row * 236;
            #pragma unroll
            for (int it = 0; it < 7; ++it) {
                const int colk = (lane & 3) * 8 + it * 32;
                *(ushort8v*)(gdst + colk) = *(const ushort8v*)(lsrc + colk);
            }
        }
    }

    // ---- PV: 7 K-steps of 32 l. A[m=n=m16][k=l], exp on read.
    #pragma unroll
    for (int step = 0; step < 7; ++step) {
        const int lloc = step * 32 + quad * 8;
        ushort8v ua = *(const ushort8v*)(pw + m16 * 236 + lloc);
        short8v af;
        #pragma unroll
        for (int j = 0; j < 8; ++j) {
            float e = __expf(bfu2f(ua[j]));
            sm += e;
            af[j] = (short)f2bfu_rn(e);
        }
        const int lg = lc + lloc;
        short8v b0 = *(const short8v*)(vt0 + lg);
        short8v b1 = *(const short8v*)(vt1 + lg);
        c0 = __builtin_amdgcn_mfma_f32_16x16x32_bf16(af, b0, c0, 0, 0, 0);
        c1 = __builtin_amdgcn_mfma_f32_16x16x32_bf16(af, b1, c1, 0, 0, 0);
    }

    sm += __shfl_xor(sm, 16);
    sm += __shfl_xor(sm, 32);
    if (lane < 16) SrowP[wave][lane] = sm;
    #pragma unroll
    for (int j = 0; j < 4; ++j) {
        partial[wave][lane][j]     = c0[j];
        partial[wave][lane][4 + j] = c1[j];
    }
    __syncthreads();

    if (t < 64) {
        float acc[8] = {0.f, 0.f, 0.f, 0.f, 0.f, 0.f, 0.f, 0.f};
        #pragma unroll
        for (int w = 0; w < 8; ++w)
            #pragma unroll
            for (int j = 0; j < 8; ++j) acc[j] += partial[w][t][j];

        const int d = t & 15, q = t >> 4;
        float* xplane = xbp + (size_t)zz * 153600;
        float* splane = Sp + (size_t)zz * 4800;
        #pragma unroll
        for (int r = 0; r < 4; ++r) {
            const int row = q * 4 + r;
            const int nn = n0 + row;
            if (nn < 300) {
                float S = 0.f;
                #pragma unroll
                for (int w = 0; w < 8; ++w) S += SrowP[w][row];
                if (d == 0) splane[(size_t)(b * 300 + nn) * 8 + h] = S;
                float* o = xplane + (size_t)(b * 300 + nn) * 256 + h * 32 + d;
                o[0]  = acc[r];
                o[16] = acc[4 + r];
            }
        }
    }
}

// ---------- output projection with fused cross-z combine + 1/S. grid 19 ----------
__global__ __launch_bounds__(256) void proj_out(
    const float* __restrict__ xbp, const float* __restrict__ Sp,
    const unsigned short* __restrict__ Wtp,
    const float* __restrict__ bp, float* __restrict__ out)
{
    const int t = threadIdx.x;
    const int wave = t >> 6, lane = t & 63;
    const int m16 = lane & 15, quad = lane >> 4;
    const int msub = (wave & 1) * 16;
    const int nc0 = (wave >> 1) * 128;
    const int m0 = blockIdx.x * 32;

    const int arow = min(m0 + msub + m16, 599);
    const float* a0p = xbp + (size_t)arow * 256 + quad * 8;

    float4v acc[8];
    #pragma unroll
    for (int i = 0; i < 8; ++i) acc[i] = (float4v){0.f, 0.f, 0.f, 0.f};

    #pragma unroll
    for (int ks = 0; ks < 8; ++ks) {
        const float S = Sp[(size_t)arow * 8 + ks]
                      + Sp[4800 + (size_t)arow * 8 + ks]
                      + Sp[9600 + (size_t)arow * 8 + ks];
        const float rS = 1.0f / S;
        float a[8];
        #pragma unroll
        for (int half = 0; half < 2; ++half) {
            const float* p = a0p + ks * 32 + half * 4;
            float4 x0 = *(const float4*)(p);
            float4 x1 = *(const float4*)(p + 153600);
            float4 x2 = *(const float4*)(p + 307200);
            a[half * 4 + 0] = (x0.x + x1.x + x2.x) * rS;
            a[half * 4 + 1] = (x0.y + x1.y + x2.y) * rS;
            a[half * 4 + 2] = (x0.z + x1.z + x2.z) * rS;
            a[half * 4 + 3] = (x0.w + x1.w + x2.w) * rS;
        }
        short8v af;
        #pragma unroll
        for (int j = 0; j < 8; ++j) af[j] = (short)f2bfu_rn(a[j]);
        #pragma unroll
        for (int i = 0; i < 8; ++i) {
            short8v bfr = *(const short8v*)(Wtp + (size_t)(nc0 + i * 16 + m16) * 256 + ks * 32 + quad * 8);
            acc[i] = __builtin_amdgcn_mfma_f32_16x16x32_bf16(af, bfr, acc[i], 0, 0, 0);
        }
    }

    #pragma unroll
    for (int i = 0; i < 8; ++i) {
        const float bv = bp[nc0 + i * 16 + m16];
        #pragma unroll
        for (int r = 0; r < 4; ++r) {
            int m = m0 + msub + quad * 4 + r;
            if (m < 600)
                out[(size_t)m * 256 + nc0 + i * 16 + m16] = acc[i][r] + bv;
        }
    }
}

// ---------- gfields: per-(b,n) folded g2[1024]+g3[256] -> global. grid 600 ----------
__global__ __launch_bounds__(256) void gfields_kernel(
    const unsigned short* __restrict__ attn,
    const float* __restrict__ W2, const float* __restrict__ b2,
    const float* __restrict__ W3, const float* __restrict__ b3,
    const float* __restrict__ Wm, float* __restrict__ gf)
{
    __shared__ float w2s[64], w3s[64], b2s[8], b3s[8], wms[24];
    const int t = threadIdx.x;
    const int bn = blockIdx.x;
    const unsigned short* ap = attn + (size_t)bn * 8 * 5376;
    float* g = gf + (size_t)bn * 1280;

    if (t < 64) { w2s[t] = W2[t]; w3s[t] = W3[t]; }
    if (t < 8)  { b2s[t] = b2[t]; b3s[t] = b3[t]; }
    if (t < 24) wms[t] = Wm[t];
    __syncthreads();

    {
        const int l2 = t * 4;
        ushort4v u[8];
        #pragma unroll
        for (int hh = 0; hh < 8; ++hh)
            u[hh] = *(const ushort4v*)(ap + hh * 5376 + 4096 + l2);
        float4 o;
        float* op = (float*)&o;
        #pragma unroll
        for (int pp = 0; pp < 4; ++pp) {
            float gg = 0.f;
            #pragma unroll
            for (int hh = 0; hh < 8; ++hh) {
                float s = b2s[hh];
                #pragma unroll
                for (int hp = 0; hp < 8; ++hp) s += bfu2f(u[hp][pp]) * w2s[hp * 8 + hh];
                gg += fmaxf(s, 0.f) * wms[8 + hh];
            }
            op[pp] = gg;
        }
        *(float4*)(g + l2) = o;
    }
    if (t < 64) {
        const int l3 = t * 4;
        ushort4v u[8];
        #pragma unroll
        for (int hh = 0; hh < 8; ++hh)
            u[hh] = *(const ushort4v*)(ap + hh * 5376 + 5120 + l3);
        float4 o;
        float* op = (float*)&o;
        #pragma unroll
        for (int pp = 0; pp < 4; ++pp) {
            float gg = 0.f;
            #pragma unroll
            for (int hh = 0; hh < 8; ++hh) {
                float s = b3s[hh];
                #pragma unroll
                for (int hp = 0; hp < 8; ++hp) s += bfu2f(u[hp][pp]) * w3s[hp * 8 + hh];
                gg += fmaxf(s, 0.f) * wms[16 + hh];
            }
            op[pp] = gg;
        }
        *(float4*)(g + 1024 + l3) = o;
    }
}

// ---------- mask pixels: FC1 + bilinear from gfields. grid (600,4), 4 px/thread ----------
__global__ __launch_bounds__(256) void mask_px(
    const unsigned short* __restrict__ attn, const float* __restrict__ gf,
    const float* __restrict__ W1, const float* __restrict__ b1,
    const float* __restrict__ Wm, const float* __restrict__ bmp,
    float* __restrict__ out)
{
    __shared__ float gs[1280];          // g2s = gs[0..1024), g3s = gs[1024..1280)
    __shared__ float w1s[64], b1s[8], wm1[8];
    __shared__ float bms;

    const int t  = threadIdx.x;
    const int bn = blockIdx.x;
    const int ph = blockIdx.y;          // pixel quarter 0..3
    const unsigned short* ap = attn + (size_t)bn * 8 * 5376;

    if (t < 64) w1s[t] = W1[t];
    if (t < 8)  { b1s[t] = b1[t]; wm1[t] = Wm[t]; }
    if (t == 0) bms = bmp[0];
    {
        const float4* src = (const float4*)(gf + (size_t)bn * 1280);
        if (t < 320) ((float4*)gs)[t] = src[t];
        else if (t - 256 < 64) { }      // only 320 vec4 loads needed; threads 0..255 do one, 0..63 extra below
    }
    if (t < 64) ((float4*)gs)[256 + t] = ((const float4*)(gf + (size_t)bn * 1280))[256 + t];
    __syncthreads();

    {
        const int p0 = ph * 1024 + t * 4;
        ushort4v u[8];
        #pragma unroll
        for (int hh = 0; hh < 8; ++hh)
            u[hh] = *(const ushort4v*)(ap + hh * 5376 + p0);

        float4 res;
        float* rp = (float*)&res;
        #pragma unroll
        for (int pp = 0; pp < 4; ++pp) {
            const int p = p0 + pp;
            const int Y = p >> 6, X = p & 63;

            float acc = bms;
            #pragma unroll
            for (int hh = 0; hh < 8; ++hh) {
                float s = b1s[hh];
                #pragma unroll
                for (int hp = 0; hp < 8; ++hp) s += bfu2f(u[hp][pp]) * w1s[hp * 8 + hh];
                acc += fmaxf(s, 0.f) * wm1[hh];
            }
            {   // g2 bilinear 32 -> 64
                float ry = fminf(fmaxf(0.5f * Y - 0.25f, 0.f), 31.f);
                float rx = fminf(fmaxf(0.5f * X - 0.25f, 0.f), 31.f);
                int y0 = (int)ry, x0 = (int)rx;
                int y1 = min(y0 + 1, 31), x1 = min(x0 + 1, 31);
                float wy = ry - (float)y0, wx = rx - (float)x0;
                acc += (gs[y0 * 32 + x0] * (1.f - wx) + gs[y0 * 32 + x1] * wx) * (1.f - wy)
                     + (gs[y1 * 32 + x0] * (1.f - wx) + gs[y1 * 32 + x1] * wx) * wy;
            }
            {   // g3 bilinear 16 -> 64
                float ry = fminf(fmaxf(0.25f * Y - 0.375f, 0.f), 15.f);
                float rx = fminf(fmaxf(0.25f * X - 0.375f, 0.f), 15.f);
                int y0 = (int)ry, x0 = (int)rx;
                int y1 = min(y0 + 1, 15), x1 = min(x0 + 1, 15);
                float wy = ry - (float)y0, wx = rx - (float)x0;
                acc += (gs[1024 + y0 * 16 + x0] * (1.f - wx) + gs[1024 + y0 * 16 + x1] * wx) * (1.f - wy)
                     + (gs[1024 + y1 * 16 + x0] * (1.f - wx) + gs[1024 + y1 * 16 + x1] * wx) * wy;
            }
            rp[pp] = fmaxf(acc, 0.f);
        }
        *(float4*)(out + 153600 + (size_t)bn * 4096 + p0) = res;
    }
}

// ---------- launch ----------
extern "C" void kernel_launch(void* const* d_in, const int* in_sizes, int n_in,
                              void* d_out, int out_size, void* d_ws, size_t ws_size,
                              hipStream_t stream) {
    const float* query = (const float*)d_in[0];
    const float* key   = (const float*)d_in[1];
    const float* value = (const float*)d_in[2];
    const float* Wq = (const float*)d_in[5];
    const float* Wk = (const float*)d_in[6];
    const float* Wv = (const float*)d_in[7];
    const float* Wp = (const float*)d_in[8];
    const float* bp = (const float*)d_in[9];
    const float* W1 = (const float*)d_in[10];
    const float* b1 = (const float*)d_in[11];
    const float* W2 = (const float*)d_in[12];
    const float* b2 = (const float*)d_in[13];
    const float* W3 = (const float*)d_in[14];
    const float* b3 = (const float*)d_in[15];
    const float* Wm = (const float*)d_in[16];
    const float* bm = (const float*)d_in[17];
    float* out = (float*)d_out;

    char* ws = (char*)d_ws;
    unsigned short* wt = (unsigned short*)(ws);       // 4*65536 bf16 = 524,288 B
    bf16*  qb   = (bf16*) (ws + 524288);              // 600*256 bf16
    bf16*  kb   = (bf16*) (ws + 831488);              // 10752*256 bf16
    bf16*  vt   = (bf16*) (ws + 6336512);             // 512*5376 bf16
    bf16*  attn = (bf16*) (ws + 11841536);            // 600*8*5376 bf16
    float* xbp  = (float*)(ws + 63451136);            // 3*600*256 fp32
    float* Sp   = (float*)(ws + 65294336);            // 3*4800 fp32
    float* gf   = (float*)(ws + 65351936);            // 600*1280 fp32 = 3,072,000 B

    cast_wt<<<dim3(4, 4, 4), 256, 0, stream>>>(Wq, Wk, Wv, Wp, wt);

    proj_all<<<691, 256, 0, stream>>>(query, key, value, wt,
        (unsigned short*)qb, (unsigned short*)kb, (unsigned short*)vt);

    attn_fused<<<dim3(19, 16, 3), 512, 0, stream>>>(
        (const unsigned short*)qb, (const unsigned short*)kb, (const unsigned short*)vt,
        (unsigned short*)attn, xbp, Sp);

    gfields_kernel<<<600, 256, 0, stream>>>(
        (const unsigned short*)attn, W2, b2, W3, b3, Wm, gf);

    mask_px<<<dim3(600, 4), 256, 0, stream>>>(
        (const unsigned short*)attn, gf, W1, b1, Wm, bm, out);

    proj_out<<<19, 256, 0, stream>>>(xbp, Sp, (const unsigned short*)wt + 196608, bp, out);
}

// Round 15
// 202.804 us; speedup vs baseline: 1.0665x; 1.0062x over previous
//
#include <hip/hip_runtime.h>
#include <hip/hip_bf16.h>

typedef __hip_bfloat16 bf16;
typedef __attribute__((ext_vector_type(8))) short short8v;          // 8 bf16 (4 VGPRs)
typedef __attribute__((ext_vector_type(8))) unsigned short ushort8v;
typedef __attribute__((ext_vector_type(4))) unsigned short ushort4v;
typedef __attribute__((ext_vector_type(4))) float float4v;

__device__ __forceinline__ float bfu2f(unsigned short u) {
    union { unsigned int i; float f; } v; v.i = ((unsigned int)u) << 16; return v.f;
}
__device__ __forceinline__ unsigned short f2bfu_rn(float x) {
    union { float f; unsigned int i; } u; u.f = x;
    unsigned int r = (u.i + 0x7FFFu + ((u.i >> 16) & 1u)) >> 16;
    return (unsigned short)r;
}

// ---------- cast+transpose weights: W[k][n] fp32 -> Wt[n][k] bf16. grid (4,4,4) ----------
__global__ __launch_bounds__(256) void cast_wt(
    const float* __restrict__ Wq, const float* __restrict__ Wk,
    const float* __restrict__ Wv, const float* __restrict__ Wp,
    unsigned short* __restrict__ wt)
{
    __shared__ unsigned short tile[64][72];
    const float* W = (blockIdx.z == 0) ? Wq : (blockIdx.z == 1) ? Wk
                   : (blockIdx.z == 2) ? Wv : Wp;
    unsigned short* WT = wt + (size_t)blockIdx.z * 65536;
    const int t = threadIdx.x;
    const int k0 = blockIdx.x * 64, n0 = blockIdx.y * 64;
    {
        const int r = t >> 2, cseg = (t & 3) * 16;
        const float* src = W + (size_t)(k0 + r) * 256 + n0 + cseg;
        #pragma unroll
        for (int j = 0; j < 16; ++j) tile[r][cseg + j] = f2bfu_rn(src[j]);
    }
    __syncthreads();
    {
        const int ch = t & 63, lq = t >> 6;
        ushort8v o0, o1;
        #pragma unroll
        for (int i = 0; i < 8; ++i) o0[i] = tile[lq * 16 + i][ch];
        #pragma unroll
        for (int i = 0; i < 8; ++i) o1[i] = tile[lq * 16 + 8 + i][ch];
        unsigned short* dst = WT + (size_t)(n0 + ch) * 256 + k0 + lq * 16;
        *(ushort8v*)(dst)     = o0;
        *(ushort8v*)(dst + 8) = o1;
    }
}

// ---------- MFMA projection core: 16 m-rows x 128 n-cols per wave ----------
__device__ __forceinline__ void proj_core(
    const float* __restrict__ aptr, const unsigned short* __restrict__ Wt,
    int nc0, int m16, int quad, float4v acc[8])
{
    #pragma unroll
    for (int i = 0; i < 8; ++i) acc[i] = (float4v){0.f, 0.f, 0.f, 0.f};
    #pragma unroll
    for (int ks = 0; ks < 8; ++ks) {
        float4 a0 = *(const float4*)(aptr + ks * 32);
        float4 a1 = *(const float4*)(aptr + ks * 32 + 4);
        short8v af;
        af[0] = (short)f2bfu_rn(a0.x); af[1] = (short)f2bfu_rn(a0.y);
        af[2] = (short)f2bfu_rn(a0.z); af[3] = (short)f2bfu_rn(a0.w);
        af[4] = (short)f2bfu_rn(a1.x); af[5] = (short)f2bfu_rn(a1.y);
        af[6] = (short)f2bfu_rn(a1.z); af[7] = (short)f2bfu_rn(a1.w);
        #pragma unroll
        for (int i = 0; i < 8; ++i) {
            short8v bfr = *(const short8v*)(Wt + (size_t)(nc0 + i * 16 + m16) * 256 + ks * 32 + quad * 8);
            acc[i] = __builtin_amdgcn_mfma_f32_16x16x32_bf16(af, bfr, acc[i], 0, 0, 0);
        }
    }
}

// ---------- fused q/k/v projections. grid 691: [0,19) q, [19,355) k, [355,691) v ----------
__global__ __launch_bounds__(256) void proj_all(
    const float* __restrict__ q, const float* __restrict__ k, const float* __restrict__ v,
    const unsigned short* __restrict__ wt,
    unsigned short* __restrict__ qb, unsigned short* __restrict__ kb,
    unsigned short* __restrict__ vt)
{
    const int t = threadIdx.x;
    const int wave = t >> 6, lane = t & 63;
    const int m16 = lane & 15, quad = lane >> 4;
    const int msub = (wave & 1) * 16;
    const int nc0 = (wave >> 1) * 128;
    const int bx = blockIdx.x;

    float4v acc[8];
    if (bx < 19) {                       // ---- query -> qb (row-major), M=600
        const int m0 = bx * 32;
        const int arow = min(m0 + msub + m16, 599);
        proj_core(q + (size_t)arow * 256 + quad * 8, wt, nc0, m16, quad, acc);
        #pragma unroll
        for (int i = 0; i < 8; ++i)
            #pragma unroll
            for (int r = 0; r < 4; ++r) {
                int m = m0 + msub + quad * 4 + r;
                if (m < 600)
                    qb[(size_t)m * 256 + nc0 + i * 16 + m16] = f2bfu_rn(acc[i][r]);
            }
    } else if (bx < 355) {               // ---- key -> kb (row-major), M=10752
        const int m0 = (bx - 19) * 32;
        proj_core(k + (size_t)(m0 + msub + m16) * 256 + quad * 8, wt + 65536, nc0, m16, quad, acc);
        #pragma unroll
        for (int i = 0; i < 8; ++i)
            #pragma unroll
            for (int r = 0; r < 4; ++r) {
                int m = m0 + msub + quad * 4 + r;
                kb[(size_t)m * 256 + nc0 + i * 16 + m16] = f2bfu_rn(acc[i][r]);
            }
    } else {                             // ---- value -> vt (transposed), M=10752
        const int m0 = (bx - 355) * 32;
        proj_core(v + (size_t)(m0 + msub + m16) * 256 + quad * 8, wt + 131072, nc0, m16, quad, acc);
        const int bb = (m0 >= 5376) ? 1 : 0;
        const int lcol = m0 - bb * 5376 + msub + quad * 4;
        #pragma unroll
        for (int i = 0; i < 8; ++i) {
            const int ch = nc0 + i * 16 + m16;
            ushort4v p;
            #pragma unroll
            for (int r = 0; r < 4; ++r) p[r] = f2bfu_rn(acc[i][r]);
            *(ushort4v*)(vt + (size_t)(bb * 256 + ch) * 5376 + lcol) = p;
        }
    }
}

// ---------- fused QK + softmax + PV, l-split x3, XCD-swizzled. grid 912, 512 thr ----------
// Block i -> XCD i&7; each XCD owns 2 (b,h) groups (57 blocks each: 19 n0 x 3 zz),
// so that XCD's L2 keeps the 688 KB k+vt slice resident across all its blocks.
__global__ __launch_bounds__(512) void attn_fused(
    const unsigned short* __restrict__ qb, const unsigned short* __restrict__ kb,
    const unsigned short* __restrict__ vt,
    unsigned short* __restrict__ attn, float* __restrict__ xbp, float* __restrict__ Sp)
{
    __shared__ unsigned short probs[8][16 * 236];   // 60,416 B
    __shared__ float partial[8][64][9];             // 18,432 B
    __shared__ float SrowP[8][16];

    const int t = threadIdx.x;
    const int wave = t >> 6, lane = t & 63;

    // XCD-aware decode (912 = 8 XCD x 114; 114 = 2 bh x 57; 57 = 19 n0 x 3 zz)
    const int i0 = blockIdx.x;
    const int c = i0 & 7;
    int m = i0 >> 3;                    // 0..113
    const int half = (m >= 57) ? 1 : 0;
    const int bh = c * 2 + half;
    m -= half * 57;
    const int n0 = (m % 19) * 16;
    const int zz = m / 19;              // 0..2

    const int b = bh >> 3, h = bh & 7;
    const int m16 = lane & 15, quad = lane >> 4;
    const float scale = 0.17677669529663687f;   // 1/sqrt(32)

    const unsigned short* qp = qb + (size_t)(b * 300 + min(n0 + m16, 299)) * 256 + h * 32 + quad * 8;
    const short8v qfrag = *(const short8v*)qp;

    const unsigned short* kbase = kb + (size_t)(b * 5376) * 256 + h * 32 + quad * 8;
    const unsigned short* vt0 = vt + (size_t)(b * 256 + h * 32 + m16) * 5376;
    const unsigned short* vt1 = vt0 + (size_t)16 * 5376;

    unsigned short* pw = &probs[wave][0];
    const int lc = zz * 1792 + wave * 224;

    float4v c0 = {0.f, 0.f, 0.f, 0.f};
    float4v c1 = {0.f, 0.f, 0.f, 0.f};
    float sm = 0.f;

    // ---- QK: 14 tiles of 16 l. A = k (m=l), B = q (n=n). C: row=l, col=n.
    #pragma unroll
    for (int i = 0; i < 14; ++i) {
        const int lcol = lc + i * 16 + m16;
        short8v kf = *(const short8v*)(kbase + (size_t)lcol * 256);
        float4v c = {0.f, 0.f, 0.f, 0.f};
        c = __builtin_amdgcn_mfma_f32_16x16x32_bf16(kf, qfrag, c, 0, 0, 0);
        ushort4v pk;
        #pragma unroll
        for (int r = 0; r < 4; ++r) pk[r] = f2bfu_rn(c[r] * scale);
        *(ushort4v*)(pw + m16 * 236 + i * 16 + quad * 4) = pk;
    }

    // ---- flush logits to global attn (for the mask kernels)
    {
        const int row = lane >> 2;
        const int n = n0 + row;
        if (n < 300) {
            unsigned short* gdst = attn + ((size_t)(b * 300 + n) * 8 + h) * 5376 + lc;
            const unsigned short* lsrc = pw + row * 236;
            #pragma unroll
            for (int it = 0; it < 7; ++it) {
                const int colk = (lane & 3) * 8 + it * 32;
                *(ushort8v*)(gdst + colk) = *(const ushort8v*)(lsrc + colk);
            }
        }
    }

    // ---- PV: 7 K-steps of 32 l. A[m=n=m16][k=l], exp on read.
    #pragma unroll
    for (int step = 0; step < 7; ++step) {
        const int lloc = step * 32 + quad * 8;
        ushort8v ua = *(const ushort8v*)(pw + m16 * 236 + lloc);
        short8v af;
        #pragma unroll
        for (int j = 0; j < 8; ++j) {
            float e = __expf(bfu2f(ua[j]));
            sm += e;
            af[j] = (short)f2bfu_rn(e);
        }
        const int lg = lc + lloc;
        short8v b0 = *(const short8v*)(vt0 + lg);
        short8v b1 = *(const short8v*)(vt1 + lg);
        c0 = __builtin_amdgcn_mfma_f32_16x16x32_bf16(af, b0, c0, 0, 0, 0);
        c1 = __builtin_amdgcn_mfma_f32_16x16x32_bf16(af, b1, c1, 0, 0, 0);
    }

    sm += __shfl_xor(sm, 16);
    sm += __shfl_xor(sm, 32);
    if (lane < 16) SrowP[wave][lane] = sm;
    #pragma unroll
    for (int j = 0; j < 4; ++j) {
        partial[wave][lane][j]     = c0[j];
        partial[wave][lane][4 + j] = c1[j];
    }
    __syncthreads();

    if (t < 64) {
        float acc[8] = {0.f, 0.f, 0.f, 0.f, 0.f, 0.f, 0.f, 0.f};
        #pragma unroll
        for (int w = 0; w < 8; ++w)
            #pragma unroll
            for (int j = 0; j < 8; ++j) acc[j] += partial[w][t][j];

        const int d = t & 15, q = t >> 4;
        float* xplane = xbp + (size_t)zz * 153600;
        float* splane = Sp + (size_t)zz * 4800;
        #pragma unroll
        for (int r = 0; r < 4; ++r) {
            const int row = q * 4 + r;
            const int nn = n0 + row;
            if (nn < 300) {
                float S = 0.f;
                #pragma unroll
                for (int w = 0; w < 8; ++w) S += SrowP[w][row];
                if (d == 0) splane[(size_t)(b * 300 + nn) * 8 + h] = S;
                float* o = xplane + (size_t)(b * 300 + nn) * 256 + h * 32 + d;
                o[0]  = acc[r];
                o[16] = acc[4 + r];
            }
        }
    }
}

// ---------- output projection with fused cross-z combine + 1/S. grid 19 ----------
__global__ __launch_bounds__(256) void proj_out(
    const float* __restrict__ xbp, const float* __restrict__ Sp,
    const unsigned short* __restrict__ Wtp,
    const float* __restrict__ bp, float* __restrict__ out)
{
    const int t = threadIdx.x;
    const int wave = t >> 6, lane = t & 63;
    const int m16 = lane & 15, quad = lane >> 4;
    const int msub = (wave & 1) * 16;
    const int nc0 = (wave >> 1) * 128;
    const int m0 = blockIdx.x * 32;

    const int arow = min(m0 + msub + m16, 599);
    const float* a0p = xbp + (size_t)arow * 256 + quad * 8;

    float4v acc[8];
    #pragma unroll
    for (int i = 0; i < 8; ++i) acc[i] = (float4v){0.f, 0.f, 0.f, 0.f};

    #pragma unroll
    for (int ks = 0; ks < 8; ++ks) {
        const float S = Sp[(size_t)arow * 8 + ks]
                      + Sp[4800 + (size_t)arow * 8 + ks]
                      + Sp[9600 + (size_t)arow * 8 + ks];
        const float rS = 1.0f / S;
        float a[8];
        #pragma unroll
        for (int half = 0; half < 2; ++half) {
            const float* p = a0p + ks * 32 + half * 4;
            float4 x0 = *(const float4*)(p);
            float4 x1 = *(const float4*)(p + 153600);
            float4 x2 = *(const float4*)(p + 307200);
            a[half * 4 + 0] = (x0.x + x1.x + x2.x) * rS;
            a[half * 4 + 1] = (x0.y + x1.y + x2.y) * rS;
            a[half * 4 + 2] = (x0.z + x1.z + x2.z) * rS;
            a[half * 4 + 3] = (x0.w + x1.w + x2.w) * rS;
        }
        short8v af;
        #pragma unroll
        for (int j = 0; j < 8; ++j) af[j] = (short)f2bfu_rn(a[j]);
        #pragma unroll
        for (int i = 0; i < 8; ++i) {
            short8v bfr = *(const short8v*)(Wtp + (size_t)(nc0 + i * 16 + m16) * 256 + ks * 32 + quad * 8);
            acc[i] = __builtin_amdgcn_mfma_f32_16x16x32_bf16(af, bfr, acc[i], 0, 0, 0);
        }
    }

    #pragma unroll
    for (int i = 0; i < 8; ++i) {
        const float bv = bp[nc0 + i * 16 + m16];
        #pragma unroll
        for (int r = 0; r < 4; ++r) {
            int m = m0 + msub + quad * 4 + r;
            if (m < 600)
                out[(size_t)m * 256 + nc0 + i * 16 + m16] = acc[i][r] + bv;
        }
    }
}

// ---------- gfields: per-(b,n) folded g2[1024]+g3[256] -> global. grid 600 ----------
__global__ __launch_bounds__(256) void gfields_kernel(
    const unsigned short* __restrict__ attn,
    const float* __restrict__ W2, const float* __restrict__ b2,
    const float* __restrict__ W3, const float* __restrict__ b3,
    const float* __restrict__ Wm, float* __restrict__ gf)
{
    __shared__ float w2s[64], w3s[64], b2s[8], b3s[8], wms[24];
    const int t = threadIdx.x;
    const int bn = blockIdx.x;
    const unsigned short* ap = attn + (size_t)bn * 8 * 5376;
    float* g = gf + (size_t)bn * 1280;

    if (t < 64) { w2s[t] = W2[t]; w3s[t] = W3[t]; }
    if (t < 8)  { b2s[t] = b2[t]; b3s[t] = b3[t]; }
    if (t < 24) wms[t] = Wm[t];
    __syncthreads();

    {
        const int l2 = t * 4;
        ushort4v u[8];
        #pragma unroll
        for (int hh = 0; hh < 8; ++hh)
            u[hh] = *(const ushort4v*)(ap + hh * 5376 + 4096 + l2);
        float4 o;
        float* op = (float*)&o;
        #pragma unroll
        for (int pp = 0; pp < 4; ++pp) {
            float gg = 0.f;
            #pragma unroll
            for (int hh = 0; hh < 8; ++hh) {
                float s = b2s[hh];
                #pragma unroll
                for (int hp = 0; hp < 8; ++hp) s += bfu2f(u[hp][pp]) * w2s[hp * 8 + hh];
                gg += fmaxf(s, 0.f) * wms[8 + hh];
            }
            op[pp] = gg;
        }
        *(float4*)(g + l2) = o;
    }
    if (t < 64) {
        const int l3 = t * 4;
        ushort4v u[8];
        #pragma unroll
        for (int hh = 0; hh < 8; ++hh)
            u[hh] = *(const ushort4v*)(ap + hh * 5376 + 5120 + l3);
        float4 o;
        float* op = (float*)&o;
        #pragma unroll
        for (int pp = 0; pp < 4; ++pp) {
            float gg = 0.f;
            #pragma unroll
            for (int hh = 0; hh < 8; ++hh) {
                float s = b3s[hh];
                #pragma unroll
                for (int hp = 0; hp < 8; ++hp) s += bfu2f(u[hp][pp]) * w3s[hp * 8 + hh];
                gg += fmaxf(s, 0.f) * wms[16 + hh];
            }
            op[pp] = gg;
        }
        *(float4*)(g + 1024 + l3) = o;
    }
}

// ---------- mask pixels: FC1 + bilinear from gfields. grid (600,4), 4 px/thread ----------
__global__ __launch_bounds__(256) void mask_px(
    const unsigned short* __restrict__ attn, const float* __restrict__ gf,
    const float* __restrict__ W1, const float* __restrict__ b1,
    const float* __restrict__ Wm, const float* __restrict__ bmp,
    float* __restrict__ out)
{
    __shared__ float gs[1280];          // g2s = gs[0..1024), g3s = gs[1024..1280)
    __shared__ float w1s[64], b1s[8], wm1[8];
    __shared__ float bms;

    const int t  = threadIdx.x;
    const int bn = blockIdx.x;
    const int ph = blockIdx.y;          // pixel quarter 0..3
    const unsigned short* ap = attn + (size_t)bn * 8 * 5376;

    if (t < 64) w1s[t] = W1[t];
    if (t < 8)  { b1s[t] = b1[t]; wm1[t] = Wm[t]; }
    if (t == 0) bms = bmp[0];
    {
        const float4* src = (const float4*)(gf + (size_t)bn * 1280);
        ((float4*)gs)[t] = src[t];
        if (t < 64) ((float4*)gs)[256 + t] = src[256 + t];
    }
    __syncthreads();

    {
        const int p0 = ph * 1024 + t * 4;
        ushort4v u[8];
        #pragma unroll
        for (int hh = 0; hh < 8; ++hh)
            u[hh] = *(const ushort4v*)(ap + hh * 5376 + p0);

        float4 res;
        float* rp = (float*)&res;
        #pragma unroll
        for (int pp = 0; pp < 4; ++pp) {
            const int p = p0 + pp;
            const int Y = p >> 6, X = p & 63;

            float acc = bms;
            #pragma unroll
            for (int hh = 0; hh < 8; ++hh) {
                float s = b1s[hh];
                #pragma unroll
                for (int hp = 0; hp < 8; ++hp) s += bfu2f(u[hp][pp]) * w1s[hp * 8 + hh];
                acc += fmaxf(s, 0.f) * wm1[hh];
            }
            {   // g2 bilinear 32 -> 64
                float ry = fminf(fmaxf(0.5f * Y - 0.25f, 0.f), 31.f);
                float rx = fminf(fmaxf(0.5f * X - 0.25f, 0.f), 31.f);
                int y0 = (int)ry, x0 = (int)rx;
                int y1 = min(y0 + 1, 31), x1 = min(x0 + 1, 31);
                float wy = ry - (float)y0, wx = rx - (float)x0;
                acc += (gs[y0 * 32 + x0] * (1.f - wx) + gs[y0 * 32 + x1] * wx) * (1.f - wy)
                     + (gs[y1 * 32 + x0] * (1.f - wx) + gs[y1 * 32 + x1] * wx) * wy;
            }
            {   // g3 bilinear 16 -> 64
                float ry = fminf(fmaxf(0.25f * Y - 0.375f, 0.f), 15.f);
                float rx = fminf(fmaxf(0.25f * X - 0.375f, 0.f), 15.f);
                int y0 = (int)ry, x0 = (int)rx;
                int y1 = min(y0 + 1, 15), x1 = min(x0 + 1, 15);
                float wy = ry - (float)y0, wx = rx - (float)x0;
                acc += (gs[1024 + y0 * 16 + x0] * (1.f - wx) + gs[1024 + y0 * 16 + x1] * wx) * (1.f - wy)
                     + (gs[1024 + y1 * 16 + x0] * (1.f - wx) + gs[1024 + y1 * 16 + x1] * wx) * wy;
            }
            rp[pp] = fmaxf(acc, 0.f);
        }
        *(float4*)(out + 153600 + (size_t)bn * 4096 + p0) = res;
    }
}

// ---------- launch ----------
extern "C" void kernel_launch(void* const* d_in, const int* in_sizes, int n_in,
                              void* d_out, int out_size, void* d_ws, size_t ws_size,
                              hipStream_t stream) {
    const float* query = (const float*)d_in[0];
    const float* key   = (const float*)d_in[1];
    const float* value = (const float*)d_in[2];
    const float* Wq = (const float*)d_in[5];
    const float* Wk = (const float*)d_in[6];
    const float* Wv = (const float*)d_in[7];
    const float* Wp = (const float*)d_in[8];
    const float* bp = (const float*)d_in[9];
    const float* W1 = (const float*)d_in[10];
    const float* b1 = (const float*)d_in[11];
    const float* W2 = (const float*)d_in[12];
    const float* b2 = (const float*)d_in[13];
    const float* W3 = (const float*)d_in[14];
    const float* b3 = (const float*)d_in[15];
    const float* Wm = (const float*)d_in[16];
    const float* bm = (const float*)d_in[17];
    float* out = (float*)d_out;

    char* ws = (char*)d_ws;
    unsigned short* wt = (unsigned short*)(ws);       // 4*65536 bf16 = 524,288 B
    bf16*  qb   = (bf16*) (ws + 524288);              // 600*256 bf16
    bf16*  kb   = (bf16*) (ws + 831488);              // 10752*256 bf16
    bf16*  vt   = (bf16*) (ws + 6336512);             // 512*5376 bf16
    bf16*  attn = (bf16*) (ws + 11841536);            // 600*8*5376 bf16
    float* xbp  = (float*)(ws + 63451136);            // 3*600*256 fp32
    float* Sp   = (float*)(ws + 65294336);            // 3*4800 fp32
    float* gf   = (float*)(ws + 65351936);            // 600*1280 fp32 = 3,072,000 B

    cast_wt<<<dim3(4, 4, 4), 256, 0, stream>>>(Wq, Wk, Wv, Wp, wt);

    proj_all<<<691, 256, 0, stream>>>(query, key, value, wt,
        (unsigned short*)qb, (unsigned short*)kb, (unsigned short*)vt);

    attn_fused<<<912, 512, 0, stream>>>(
        (const unsigned short*)qb, (const unsigned short*)kb, (const unsigned short*)vt,
        (unsigned short*)attn, xbp, Sp);

    gfields_kernel<<<600, 256, 0, stream>>>(
        (const unsigned short*)attn, W2, b2, W3, b3, Wm, gf);

    mask_px<<<dim3(600, 4), 256, 0, stream>>>(
        (const unsigned short*)attn, gf, W1, b1, Wm, bm, out);

    proj_out<<<19, 256, 0, stream>>>(xbp, Sp, (const unsigned short*)wt + 196608, bp, out);
}